// Round 2
// baseline (1387.629 us; speedup 1.0000x reference)
//
#include <hip/hip_runtime.h>
#include <hip/hip_bf16.h>

#define D_INN 4096
#define D_OUTT 4096
#define BSZ 8
#define SEQ 2048
#define NROWS (BSZ*SEQ)
#define NE 8
#define RE 8
#define RTOT 64
#define TEDIM 64
#define SCALING 0.25f

typedef __attribute__((ext_vector_type(8))) short bf16x8;
typedef __attribute__((ext_vector_type(4))) float f32x4;
typedef __attribute__((ext_vector_type(8))) unsigned short ushort8;

__device__ __forceinline__ unsigned short f2bf(float f) {
  union { float f; unsigned u; } v; v.f = f;
  unsigned r = v.u + 0x7FFF + ((v.u >> 16) & 1);
  return (unsigned short)(r >> 16);
}

__device__ __forceinline__ void gl_lds16(const void* g, void* l) {
  __builtin_amdgcn_global_load_lds(
      (const __attribute__((address_space(1))) void*)g,
      (__attribute__((address_space(3))) void*)l, 16, 0, 0);
}

// ---------------- fp32 -> bf16 convert, 8 elems/thread ----------------
__global__ void cvt_kernel(const float* __restrict__ in,
                           unsigned short* __restrict__ out, int n8) {
  int i = blockIdx.x * 256 + threadIdx.x;
  if (i >= n8) return;
  const float4* p = (const float4*)in + (size_t)i * 2;
  float4 a = p[0], b = p[1];
  ushort8 o;
  o[0] = f2bf(a.x); o[1] = f2bf(a.y); o[2] = f2bf(a.z); o[3] = f2bf(a.w);
  o[4] = f2bf(b.x); o[5] = f2bf(b.y); o[6] = f2bf(b.z); o[7] = f2bf(b.w);
  *((ushort8*)out + i) = o;
}

// ---------------- gate: gw[b][e] = softmax_e(task_emb[task_id[b]] . gate_W[e]) ----
__global__ void gate_kernel(const int* __restrict__ task_id,
                            const float* __restrict__ task_emb,
                            const float* __restrict__ gate_W,
                            float* __restrict__ gw) {
  __shared__ float logits[BSZ][NE];
  int t = threadIdx.x;
  if (t < BSZ * NE) {
    int b = t >> 3, e = t & 7;
    const float* temb = task_emb + (size_t)task_id[b] * TEDIM;
    const float* g = gate_W + (size_t)e * TEDIM;
    float s = 0.f;
    for (int k = 0; k < TEDIM; ++k) s += temb[k] * g[k];
    logits[b][e] = s;
  }
  __syncthreads();
  if (t < BSZ) {
    float m = -1e30f;
    for (int e = 0; e < NE; ++e) m = fmaxf(m, logits[t][e]);
    float ex[NE]; float sum = 0.f;
    for (int e = 0; e < NE; ++e) { ex[e] = expf(logits[t][e] - m); sum += ex[e]; }
    for (int e = 0; e < NE; ++e) gw[t * NE + e] = ex[e] / sum;
  }
}

// ---------------- Wbg[b][o][e*8+r] = bf16(scaling * gw[b][e] * Wb[e][o][r]) ------
__global__ void build_wbg(const float* __restrict__ Wb,
                          const float* __restrict__ gw,
                          unsigned short* __restrict__ wbg) {
  int idx = blockIdx.x * 256 + threadIdx.x;
  if (idx >= BSZ * D_OUTT * RTOT) return;
  int b = idx >> 18;           // 4096*64 = 2^18
  int rem = idx & 262143;
  int o = rem >> 6;
  int er = rem & 63;
  int e = er >> 3, r = er & 7;
  float v = SCALING * gw[b * NE + e] * Wb[((size_t)e * D_OUTT + o) * RE + r];
  wbg[idx] = f2bf(v);
}

// ---------------- h = x @ Wa^T : [16384,64] bf16, K=4096 -------------------------
__global__ __launch_bounds__(256) void h_gemm(const unsigned short* __restrict__ xbf,
                                              const unsigned short* __restrict__ abf,
                                              unsigned short* __restrict__ hbf) {
  __shared__ short Xs[128 * 32];
  __shared__ short Ws[64 * 32];
  int tid = threadIdx.x, lane = tid & 63, wid = tid >> 6;
  int mBase = blockIdx.x * 128;
  int lr = lane & 15, lk = (lane >> 4) * 8;
  f32x4 acc[2][4] = {};
  for (int kk = 0; kk < D_INN; kk += 32) {
    __syncthreads();
#pragma unroll
    for (int p = 0; p < 2; ++p) {
      int idx = p * 256 + tid;
      int r = idx >> 2, c = idx & 3;
      gl_lds16(xbf + (size_t)(mBase + r) * D_INN + kk + c * 8, &Xs[idx * 8]);
    }
    {
      int r = tid >> 2, c = tid & 3;
      gl_lds16(abf + (size_t)r * D_INN + kk + c * 8, &Ws[tid * 8]);
    }
    __syncthreads();
    bf16x8 af[2], bf[4];
#pragma unroll
    for (int i = 0; i < 2; ++i)
      af[i] = *(const bf16x8*)&Xs[(wid * 32 + i * 16 + lr) * 32 + lk];
#pragma unroll
    for (int j = 0; j < 4; ++j)
      bf[j] = *(const bf16x8*)&Ws[(j * 16 + lr) * 32 + lk];
#pragma unroll
    for (int i = 0; i < 2; ++i)
#pragma unroll
      for (int j = 0; j < 4; ++j)
        acc[i][j] = __builtin_amdgcn_mfma_f32_16x16x32_bf16(af[i], bf[j], acc[i][j], 0, 0, 0);
  }
  int lhi = lane >> 4;
  for (int i = 0; i < 2; ++i)
    for (int j = 0; j < 4; ++j)
      for (int q = 0; q < 4; ++q) {
        int row = mBase + wid * 32 + i * 16 + lhi * 4 + q;
        int col = j * 16 + lr;
        hbf[(size_t)row * RTOT + col] = f2bf(acc[i][j][q]);
      }
}

// ---------------- main: out = x@W^T + b + h@Wbg^T (m97 128^2 structure) ----------
__global__ __launch_bounds__(256) void main_gemm(
    const unsigned short* __restrict__ xbf,
    const unsigned short* __restrict__ wbf,
    const unsigned short* __restrict__ hbf,
    const unsigned short* __restrict__ wbg,
    const float* __restrict__ base_b,
    float* __restrict__ out) {
  __shared__ short smem[16384];   // 32 KB
  short* As = smem;               // [128][32] during K-loop
  short* Bs = smem + 4096;
  int tid = threadIdx.x, lane = tid & 63, wid = tid >> 6;
  int bid = blockIdx.x;
  int wg = (bid & 7) * 512 + (bid >> 3);  // bijective XCD swizzle (4096 % 8 == 0)
  int ntile = wg & 31, mtile = wg >> 5;
  int rowBase = mtile * 128, colBase = ntile * 128;
  int wm = wid >> 1, wn = wid & 1;
  int lr = lane & 15, lk = (lane >> 4) * 8;
  f32x4 acc[4][4] = {};
  for (int kk = 0; kk < D_INN; kk += 32) {
    __syncthreads();
#pragma unroll
    for (int p = 0; p < 2; ++p) {
      int idx = p * 256 + tid;
      int r = idx >> 2, c = idx & 3;
      gl_lds16(xbf + (size_t)(rowBase + r) * D_INN + kk + c * 8, &As[idx * 8]);
    }
#pragma unroll
    for (int p = 0; p < 2; ++p) {
      int idx = p * 256 + tid;
      int r = idx >> 2, c = idx & 3;
      gl_lds16(wbf + (size_t)(colBase + r) * D_INN + kk + c * 8, &Bs[idx * 8]);
    }
    __syncthreads();
    bf16x8 af[4], bf[4];
#pragma unroll
    for (int i = 0; i < 4; ++i)
      af[i] = *(const bf16x8*)&As[(wm * 64 + i * 16 + lr) * 32 + lk];
#pragma unroll
    for (int j = 0; j < 4; ++j)
      bf[j] = *(const bf16x8*)&Bs[(wn * 64 + j * 16 + lr) * 32 + lk];
#pragma unroll
    for (int i = 0; i < 4; ++i)
#pragma unroll
      for (int j = 0; j < 4; ++j)
        acc[i][j] = __builtin_amdgcn_mfma_f32_16x16x32_bf16(af[i], bf[j], acc[i][j], 0, 0, 0);
  }
  // ---- LoRA epilogue: 2 extra K-steps over rank-64 with h-tile and Wbg-tile ----
  short* Hs = smem;          // [128][64]
  short* Gs = smem + 8192;   // [128][64]
  int bIdx = rowBase >> 11;  // S=2048 rows per batch; tile never crosses batch
  __syncthreads();
#pragma unroll
  for (int p = 0; p < 4; ++p) {
    int idx = p * 256 + tid;
    int r = idx >> 3, c = idx & 7;
    gl_lds16(hbf + (size_t)(rowBase + r) * RTOT + c * 8, &Hs[idx * 8]);
  }
#pragma unroll
  for (int p = 0; p < 4; ++p) {
    int idx = p * 256 + tid;
    int r = idx >> 3, c = idx & 7;
    gl_lds16(wbg + ((size_t)bIdx * D_OUTT + colBase + r) * RTOT + c * 8, &Gs[idx * 8]);
  }
  __syncthreads();
#pragma unroll
  for (int kk2 = 0; kk2 < 64; kk2 += 32) {
    bf16x8 haf[4], gbf[4];
#pragma unroll
    for (int i = 0; i < 4; ++i)
      haf[i] = *(const bf16x8*)&Hs[(wm * 64 + i * 16 + lr) * 64 + kk2 + lk];
#pragma unroll
    for (int j = 0; j < 4; ++j)
      gbf[j] = *(const bf16x8*)&Gs[(wn * 64 + j * 16 + lr) * 64 + kk2 + lk];
#pragma unroll
    for (int i = 0; i < 4; ++i)
#pragma unroll
      for (int j = 0; j < 4; ++j)
        acc[i][j] = __builtin_amdgcn_mfma_f32_16x16x32_bf16(haf[i], gbf[j], acc[i][j], 0, 0, 0);
  }
  // ---- write out: fp32 + bias ----
  float biasv[4];
#pragma unroll
  for (int j = 0; j < 4; ++j)
    biasv[j] = base_b[colBase + wn * 64 + j * 16 + lr];
  int lhi = lane >> 4;
  for (int i = 0; i < 4; ++i) {
    int gm = rowBase + wm * 64 + i * 16 + lhi * 4;
    for (int j = 0; j < 4; ++j) {
      int gn = colBase + wn * 64 + j * 16 + lr;
      for (int q = 0; q < 4; ++q)
        out[(size_t)(gm + q) * D_OUTT + gn] = acc[i][j][q] + biasv[j];
    }
  }
}

extern "C" void kernel_launch(void* const* d_in, const int* in_sizes, int n_in,
                              void* d_out, int out_size, void* d_ws, size_t ws_size,
                              hipStream_t stream) {
  const float* x        = (const float*)d_in[0];
  const int*   task_id  = (const int*)d_in[1];
  const float* base_W   = (const float*)d_in[2];
  const float* base_b   = (const float*)d_in[3];
  const float* Wa       = (const float*)d_in[4];
  const float* Wb       = (const float*)d_in[5];
  const float* task_emb = (const float*)d_in[6];
  const float* gate_W   = (const float*)d_in[7];
  float* out = (float*)d_out;

  char* ws = (char*)d_ws;
  // workspace layout (all offsets 256KB-aligned)
  unsigned short* xbf = (unsigned short*)(ws);                 // 128 MB
  unsigned short* wbf = (unsigned short*)(ws + 134217728);     //  32 MB
  unsigned short* abf = (unsigned short*)(ws + 167772160);     // 0.5 MB
  unsigned short* hbf = (unsigned short*)(ws + 168296448);     //   2 MB
  unsigned short* wbg = (unsigned short*)(ws + 170393600);     //   4 MB
  float*          gw  = (float*)(ws + 174587904);              // 256 B

  gate_kernel<<<1, 64, 0, stream>>>(task_id, task_emb, gate_W, gw);
  build_wbg<<<(BSZ * D_OUTT * RTOT) / 256, 256, 0, stream>>>(Wb, gw, wbg);
  cvt_kernel<<<(NROWS * D_INN / 8) / 256, 256, 0, stream>>>(x, xbf, NROWS * D_INN / 8);
  cvt_kernel<<<(D_OUTT * D_INN / 8) / 256, 256, 0, stream>>>(base_W, wbf, D_OUTT * D_INN / 8);
  cvt_kernel<<<(NE * RE * D_INN / 8) / 256, 256, 0, stream>>>(Wa, abf, NE * RE * D_INN / 8);
  h_gemm<<<NROWS / 128, 256, 0, stream>>>(xbf, abf, hbf);
  main_gemm<<<(NROWS / 128) * (D_OUTT / 128), 256, 0, stream>>>(xbf, wbf, hbf, wbg, base_b, out);
}

// Round 3
// 960.060 us; speedup vs baseline: 1.4454x; 1.4454x over previous
//
#include <hip/hip_runtime.h>
#include <hip/hip_bf16.h>

#define D_INN 4096
#define D_OUTT 4096
#define BSZ 8
#define SEQ 2048
#define NROWS (BSZ*SEQ)
#define NE 8
#define RE 8
#define RTOT 64
#define TEDIM 64
#define SCALING 0.25f
#define NKT 128   // K tiles of 32

typedef __attribute__((ext_vector_type(8))) short bf16x8;
typedef __attribute__((ext_vector_type(4))) float f32x4;
typedef __attribute__((ext_vector_type(8))) unsigned short ushort8;
typedef __attribute__((ext_vector_type(4))) float fvec4;

__device__ __forceinline__ unsigned short f2bf(float f) {
  union { float f; unsigned u; } v; v.f = f;
  unsigned r = v.u + 0x7FFF + ((v.u >> 16) & 1);
  return (unsigned short)(r >> 16);
}

__device__ __forceinline__ void gl_lds16(const void* g, void* l) {
  __builtin_amdgcn_global_load_lds(
      (const __attribute__((address_space(1))) void*)g,
      (__attribute__((address_space(3))) void*)l, 16, 0, 0);
}

// ---------------- fp32 -> bf16 convert, 8 elems/thread (nt loads) --------------
__global__ void cvt_kernel(const float* __restrict__ in,
                           unsigned short* __restrict__ out, int n8) {
  int i = blockIdx.x * 256 + threadIdx.x;
  if (i >= n8) return;
  const fvec4* p = (const fvec4*)in + (size_t)i * 2;
  fvec4 a = __builtin_nontemporal_load(p);
  fvec4 b = __builtin_nontemporal_load(p + 1);
  ushort8 o;
  o[0] = f2bf(a[0]); o[1] = f2bf(a[1]); o[2] = f2bf(a[2]); o[3] = f2bf(a[3]);
  o[4] = f2bf(b[0]); o[5] = f2bf(b[1]); o[6] = f2bf(b[2]); o[7] = f2bf(b[3]);
  *((ushort8*)out + i) = o;
}

// ---------------- gate ---------------------------------------------------------
__global__ void gate_kernel(const int* __restrict__ task_id,
                            const float* __restrict__ task_emb,
                            const float* __restrict__ gate_W,
                            float* __restrict__ gw) {
  __shared__ float logits[BSZ][NE];
  int t = threadIdx.x;
  if (t < BSZ * NE) {
    int b = t >> 3, e = t & 7;
    const float* temb = task_emb + (size_t)task_id[b] * TEDIM;
    const float* g = gate_W + (size_t)e * TEDIM;
    float s = 0.f;
    for (int k = 0; k < TEDIM; ++k) s += temb[k] * g[k];
    logits[b][e] = s;
  }
  __syncthreads();
  if (t < BSZ) {
    float m = -1e30f;
    for (int e = 0; e < NE; ++e) m = fmaxf(m, logits[t][e]);
    float ex[NE]; float sum = 0.f;
    for (int e = 0; e < NE; ++e) { ex[e] = expf(logits[t][e] - m); sum += ex[e]; }
    for (int e = 0; e < NE; ++e) gw[t * NE + e] = ex[e] / sum;
  }
}

// ---------------- Wbg[b][o][e*8+r] ---------------------------------------------
__global__ void build_wbg(const float* __restrict__ Wb,
                          const float* __restrict__ gw,
                          unsigned short* __restrict__ wbg) {
  int idx = blockIdx.x * 256 + threadIdx.x;
  if (idx >= BSZ * D_OUTT * RTOT) return;
  int b = idx >> 18;
  int rem = idx & 262143;
  int o = rem >> 6;
  int er = rem & 63;
  int e = er >> 3, r = er & 7;
  float v = SCALING * gw[b * NE + e] * Wb[((size_t)e * D_OUTT + o) * RE + r];
  wbg[idx] = f2bf(v);
}

// ---------------- h partial: x @ Wa^T over K-chunk, fp32 out -------------------
__global__ __launch_bounds__(256) void h_gemm(const unsigned short* __restrict__ xbf,
                                              const unsigned short* __restrict__ abf,
                                              float* __restrict__ hp) {
  __shared__ short Xs[128 * 32];
  __shared__ short Ws[64 * 32];
  int tid = threadIdx.x, lane = tid & 63, wid = tid >> 6;
  int mBase = blockIdx.x * 128;
  int k0 = blockIdx.y * (D_INN / 4);
  int lr = lane & 15, lk = (lane >> 4) * 8;
  f32x4 acc[2][4] = {};
  for (int kk = k0; kk < k0 + D_INN / 4; kk += 32) {
    __syncthreads();
#pragma unroll
    for (int p = 0; p < 2; ++p) {
      int idx = p * 256 + tid;
      int r = idx >> 2, c = idx & 3;
      gl_lds16(xbf + (size_t)(mBase + r) * D_INN + kk + c * 8, &Xs[idx * 8]);
    }
    {
      int r = tid >> 2, c = tid & 3;
      gl_lds16(abf + (size_t)r * D_INN + kk + c * 8, &Ws[tid * 8]);
    }
    __syncthreads();
    bf16x8 af[2], bfr[4];
#pragma unroll
    for (int i = 0; i < 2; ++i)
      af[i] = *(const bf16x8*)&Xs[(wid * 32 + i * 16 + lr) * 32 + lk];
#pragma unroll
    for (int j = 0; j < 4; ++j)
      bfr[j] = *(const bf16x8*)&Ws[(j * 16 + lr) * 32 + lk];
#pragma unroll
    for (int i = 0; i < 2; ++i)
#pragma unroll
      for (int j = 0; j < 4; ++j)
        acc[i][j] = __builtin_amdgcn_mfma_f32_16x16x32_bf16(af[i], bfr[j], acc[i][j], 0, 0, 0);
  }
  int lhi = lane >> 4;
  float* hpo = hp + (size_t)blockIdx.y * NROWS * RTOT;
  for (int i = 0; i < 2; ++i)
    for (int j = 0; j < 4; ++j)
      for (int q = 0; q < 4; ++q) {
        int row = mBase + wid * 32 + i * 16 + lhi * 4 + q;
        int col = j * 16 + lr;
        hpo[(size_t)row * RTOT + col] = acc[i][j][q];
      }
}

// ---------------- reduce 4 h-partials -> bf16 ----------------------------------
__global__ void reduce_h(const float* __restrict__ hp,
                         unsigned short* __restrict__ hbf) {
  int i = blockIdx.x * 256 + threadIdx.x;   // over NROWS*RTOT = 1048576
  const int st = NROWS * RTOT;
  float s = hp[i] + hp[i + st] + hp[i + 2 * st] + hp[i + 3 * st];
  hbf[i] = f2bf(s);
}

// ---------------- main: 256x256 tile, 3-buffer counted-vmcnt pipeline ----------
__global__ __launch_bounds__(512, 2) void main_gemm(
    const unsigned short* __restrict__ xbf,
    const unsigned short* __restrict__ wbf,
    const unsigned short* __restrict__ hbf,
    const unsigned short* __restrict__ wbg,
    const float* __restrict__ base_b,
    float* __restrict__ out) {
  __shared__ short smem[49152];   // 96 KB: 3 bufs x (A[256][32] + B[256][32])
  int tid = threadIdx.x, lane = tid & 63, wid = tid >> 6;
  int wm = wid >> 2, wn = wid & 3;          // 2 x 4 waves, each 128x64 out
  int lr = lane & 15, hi = lane >> 4;
  int aslot = ((hi ^ (lr & 3)) << 3);       // swizzled slot offset (shorts)

  int bid = blockIdx.x;
  int wg = (bid & 7) * 128 + (bid >> 3);    // bijective XCD swizzle (1024 % 8 == 0)
  int ntile = wg & 15, mtile = wg >> 4;
  int rowBase = mtile * 256, colBase = ntile * 256;

  // staging source addresses (pre-swizzled columns; rule #21)
  int sr = tid >> 2, sc = tid & 3;
  int scol = ((sc ^ (sr & 3)) << 3);
  const unsigned short* aSrc0 = xbf + (size_t)(rowBase + sr) * D_INN + scol;
  const unsigned short* aSrc1 = xbf + (size_t)(rowBase + 128 + sr) * D_INN + scol;
  const unsigned short* bSrc0 = wbf + (size_t)(colBase + sr) * D_INN + scol;
  const unsigned short* bSrc1 = wbf + (size_t)(colBase + 128 + sr) * D_INN + scol;

  f32x4 acc[8][4] = {};

  // prologue: stage tiles 0,1 into bufs 0,1 (8 loads/thread)
#pragma unroll
  for (int tt = 0; tt < 2; ++tt) {
    int kk = tt * 32;
    short* dA = &smem[tt * 16384];
    short* dB = dA + 8192;
    gl_lds16(aSrc0 + kk, dA + tid * 8);
    gl_lds16(aSrc1 + kk, dA + 4096 + tid * 8);
    gl_lds16(bSrc0 + kk, dB + tid * 8);
    gl_lds16(bSrc1 + kk, dB + 4096 + tid * 8);
  }

  int rb = 0;
  for (int t = 0; t < NKT; ++t) {
    if (t < NKT - 1) asm volatile("s_waitcnt vmcnt(4)" ::: "memory");
    else             asm volatile("s_waitcnt vmcnt(0)" ::: "memory");
    __builtin_amdgcn_s_barrier();
    asm volatile("" ::: "memory");
    short* A0 = &smem[rb * 16384];
    short* B0 = A0 + 8192;
    int sb = rb + 2; if (sb >= 3) sb -= 3;
    bool doStage = (t + 2 < NKT);
    int kk2 = (t + 2) * 32;
    // ---- phase 0: stage A(t+2) | read B frags + A frags 0-3 | 16 MFMA ----
    if (doStage) {
      short* dA = &smem[sb * 16384];
      gl_lds16(aSrc0 + kk2, dA + tid * 8);
      gl_lds16(aSrc1 + kk2, dA + 4096 + tid * 8);
    }
    bf16x8 bfr[4];
#pragma unroll
    for (int j = 0; j < 4; ++j)
      bfr[j] = *(const bf16x8*)&B0[(wn * 64 + j * 16 + lr) * 32 + aslot];
    bf16x8 afr[4];
#pragma unroll
    for (int i = 0; i < 4; ++i)
      afr[i] = *(const bf16x8*)&A0[(wm * 128 + i * 16 + lr) * 32 + aslot];
    __builtin_amdgcn_s_setprio(1);
#pragma unroll
    for (int i = 0; i < 4; ++i)
#pragma unroll
      for (int j = 0; j < 4; ++j)
        acc[i][j] = __builtin_amdgcn_mfma_f32_16x16x32_bf16(afr[i], bfr[j], acc[i][j], 0, 0, 0);
    __builtin_amdgcn_s_setprio(0);
    // ---- phase 1: stage B(t+2) | read A frags 4-7 | 16 MFMA ----
    if (doStage) {
      short* dB = &smem[sb * 16384 + 8192];
      gl_lds16(bSrc0 + kk2, dB + tid * 8);
      gl_lds16(bSrc1 + kk2, dB + 4096 + tid * 8);
    }
#pragma unroll
    for (int i = 0; i < 4; ++i)
      afr[i] = *(const bf16x8*)&A0[(wm * 128 + (i + 4) * 16 + lr) * 32 + aslot];
    __builtin_amdgcn_s_setprio(1);
#pragma unroll
    for (int i = 0; i < 4; ++i)
#pragma unroll
      for (int j = 0; j < 4; ++j)
        acc[i + 4][j] = __builtin_amdgcn_mfma_f32_16x16x32_bf16(afr[i], bfr[j], acc[i + 4][j], 0, 0, 0);
    __builtin_amdgcn_s_setprio(0);
    rb = rb + 1; if (rb >= 3) rb = 0;
  }

  // ---- LoRA epilogue: K=64 with H[256][64] and G[256][64] (128B-row swizzle) ----
  __builtin_amdgcn_s_barrier();
  asm volatile("" ::: "memory");
  int bIdx = rowBase >> 11;
  {
    int r0 = tid >> 3;
    int sc8 = (((tid & 7) ^ (r0 & 7)) << 3);
#pragma unroll
    for (int p = 0; p < 4; ++p) {
      int row = p * 64 + r0;
      gl_lds16(hbf + (size_t)(rowBase + row) * RTOT + sc8, &smem[(p * 512 + tid) * 8]);
    }
#pragma unroll
    for (int p = 0; p < 4; ++p) {
      int row = p * 64 + r0;
      gl_lds16(wbg + ((size_t)bIdx * D_OUTT + colBase + row) * RTOT + sc8,
               &smem[16384 + (p * 512 + tid) * 8]);
    }
  }
  asm volatile("s_waitcnt vmcnt(0)" ::: "memory");
  __builtin_amdgcn_s_barrier();
  asm volatile("" ::: "memory");
  int lslot = lr & 7;
#pragma unroll
  for (int ks = 0; ks < 2; ++ks) {
    int hoff = (((ks * 4 + hi) ^ lslot) << 3);
    bf16x8 gfr[4];
#pragma unroll
    for (int j = 0; j < 4; ++j)
      gfr[j] = *(const bf16x8*)&smem[16384 + (wn * 64 + j * 16 + lr) * 64 + hoff];
#pragma unroll
    for (int i = 0; i < 8; ++i) {
      bf16x8 hfr = *(const bf16x8*)&smem[(wm * 128 + i * 16 + lr) * 64 + hoff];
#pragma unroll
      for (int j = 0; j < 4; ++j)
        acc[i][j] = __builtin_amdgcn_mfma_f32_16x16x32_bf16(hfr, gfr[j], acc[i][j], 0, 0, 0);
    }
  }

  // ---- write out: fp32 + bias, nontemporal ----
  float biasv[4];
#pragma unroll
  for (int j = 0; j < 4; ++j)
    biasv[j] = base_b[colBase + wn * 64 + j * 16 + lr];
#pragma unroll
  for (int i = 0; i < 8; ++i) {
    int gm = rowBase + wm * 128 + i * 16 + hi * 4;
#pragma unroll
    for (int j = 0; j < 4; ++j) {
      int gn = colBase + wn * 64 + j * 16 + lr;
#pragma unroll
      for (int q = 0; q < 4; ++q)
        __builtin_nontemporal_store(acc[i][j][q] + biasv[j],
                                    &out[(size_t)(gm + q) * D_OUTT + gn]);
    }
  }
}

extern "C" void kernel_launch(void* const* d_in, const int* in_sizes, int n_in,
                              void* d_out, int out_size, void* d_ws, size_t ws_size,
                              hipStream_t stream) {
  const float* x        = (const float*)d_in[0];
  const int*   task_id  = (const int*)d_in[1];
  const float* base_W   = (const float*)d_in[2];
  const float* base_b   = (const float*)d_in[3];
  const float* Wa       = (const float*)d_in[4];
  const float* Wb       = (const float*)d_in[5];
  const float* task_emb = (const float*)d_in[6];
  const float* gate_W   = (const float*)d_in[7];
  float* out = (float*)d_out;

  char* ws = (char*)d_ws;
  unsigned short* xbf = (unsigned short*)(ws);                 // 128 MB
  unsigned short* wbf = (unsigned short*)(ws + 134217728);     //  32 MB
  unsigned short* abf = (unsigned short*)(ws + 167772160);     // 0.5 MB
  unsigned short* hbf = (unsigned short*)(ws + 168296448);     //   2 MB
  unsigned short* wbg = (unsigned short*)(ws + 170393600);     //   4 MB
  float*          gw  = (float*)(ws + 174587904);              // 256 B
  float*          hp  = (float*)d_out;                         // 16 MB scratch in d_out head

  gate_kernel<<<1, 64, 0, stream>>>(task_id, task_emb, gate_W, gw);
  build_wbg<<<(BSZ * D_OUTT * RTOT) / 256, 256, 0, stream>>>(Wb, gw, wbg);
  cvt_kernel<<<(NROWS * D_INN / 8) / 256, 256, 0, stream>>>(x, xbf, NROWS * D_INN / 8);
  cvt_kernel<<<(D_OUTT * D_INN / 8) / 256, 256, 0, stream>>>(base_W, wbf, D_OUTT * D_INN / 8);
  cvt_kernel<<<(NE * RE * D_INN / 8) / 256, 256, 0, stream>>>(Wa, abf, NE * RE * D_INN / 8);
  h_gemm<<<dim3(NROWS / 128, 4), 256, 0, stream>>>(xbf, abf, hp);
  reduce_h<<<(NROWS * RTOT) / 256, 256, 0, stream>>>(hp, hbf);
  main_gemm<<<(NROWS / 256) * (D_OUTT / 256), 512, 0, stream>>>(xbf, wbf, hbf, wbg, base_b, out);
}